// Round 1
// 361.977 us; speedup vs baseline: 1.0863x; 1.0863x over previous
//
#include <hip/hip_runtime.h>
#include <math.h>

#define SEQ 8192
#define HDIM 1024
#define FDIM 128
#define NPART 256   // qsum partial blocks

typedef float f4 __attribute__((ext_vector_type(4)));

// workspace layout (floats)
#define WS_PART   0                       // 256*1024 = 262144
#define WS_G      262144                  // 2*1024   (g0 | g1)
#define WS_CMEM   264192                  // 2*128    (mem_k @ Wa1[:128])
#define WS_CPART  264448                  // 8*128    (qmean @ Wa1[128:])
#define WS_D0     265472                  // 8192
#define WS_D1     273664                  // 8192
#define WS_WC     281856                  // 2        (0.5*sigmoid weights)

// ---------------------------------------------------------------------------
// K1: role-split grid, 261 blocks x 256 threads.
//   blocks 0..3 : g_k[h] = bg[h] + mem_k @ Wg[:,h]       (h = bx*256+tid)
//   block  4    : cmem[k][i] = mem_k @ Wa1[0:128, i]
//   blocks 5..260: partial column sums of query -> part[256][1024]
// The tiny mem/g/cmem work runs concurrently with the 32 MB query read.
// ---------------------------------------------------------------------------
__global__ void __launch_bounds__(256)
k1_qsum_g(const float* __restrict__ q,
          const float* __restrict__ ts, const float* __restrict__ dg,
          const float* __restrict__ Wt1, const float* __restrict__ bt1,
          const float* __restrict__ Wt2, const float* __restrict__ bt2,
          const float* __restrict__ Wg,  const float* __restrict__ bg,
          const float* __restrict__ Wa1,
          float* __restrict__ part, float* __restrict__ g,
          float* __restrict__ cmem) {
    __shared__ float s_mem[2 * FDIM];
    const int tid = threadIdx.x;
    const int bx  = blockIdx.x;

    if (bx >= 5) {
        // ---- qsum partial: block sums 32 rows, thread owns float4-column tid
        const int blk = bx - 5;
        const int rows = SEQ / NPART;          // 32
        const int r0 = blk * rows;
        const f4* q4 = (const f4*)q;
        f4 acc = {0.f, 0.f, 0.f, 0.f};
        #pragma unroll 8
        for (int r = 0; r < rows; ++r)
            acc += q4[(size_t)(r0 + r) * (HDIM / 4) + tid];
        ((f4*)part)[blk * (HDIM / 4) + tid] = acc;
        return;
    }

    // ---- temporal MLP -> s_mem (redundant per small block; 16 KB read)
    {
        const int k = tid >> 7, i = tid & 127;
        const float t = ts[k];
        float acc = bt2[i];
        #pragma unroll
        for (int j = 0; j < 32; ++j) {
            float hj = fmaxf(t * Wt1[j] + bt1[j], 0.0f);
            acc += hj * Wt2[j * FDIM + i];
        }
        s_mem[tid] = dg[tid] + acc;
    }
    __syncthreads();

    if (bx < 4) {
        // ---- g_k[h]: 4 blocks x 256 h-columns, both k per thread (shared Wg load)
        const int h = bx * 256 + tid;
        float g0 = bg[h], g1 = g0;
        #pragma unroll 8
        for (int f = 0; f < FDIM; ++f) {
            const float w = Wg[f * HDIM + h];
            g0 += s_mem[f] * w;
            g1 += s_mem[FDIM + f] * w;
        }
        g[h] = g0;
        g[HDIM + h] = g1;
    } else {
        // ---- bx == 4: cmem[k][i] = sum_f mem[k][f] * Wa1[f*128 + i]
        const int k = tid >> 7, i = tid & 127;
        float acc = 0.f;
        #pragma unroll 8
        for (int f = 0; f < FDIM; ++f)
            acc += s_mem[k * FDIM + f] * Wa1[f * FDIM + i];
        cmem[tid] = acc;
    }
}

// ---------------------------------------------------------------------------
// K2: role-split grid, 2056 blocks x 256 threads.
//   blocks 0..7   : qmean over 128 h-columns each + cpart[b][i] = qm @ Wa1[128+h, i]
//   blocks 8..2055: d_k[row] = g_k . key[row]   (one wave per row, both k)
// The former single-block 1 MB part-reduce + 0.5 MB Wa1 read is now spread
// over 8 CUs and overlapped with the 32 MB key read.
// ---------------------------------------------------------------------------
__global__ void __launch_bounds__(256)
k2_rowdot_qmean(const float* __restrict__ key, const float* __restrict__ part,
                const float* __restrict__ Wa1, const float* __restrict__ g,
                float* __restrict__ d0, float* __restrict__ d1,
                float* __restrict__ cpart) {
    __shared__ float s_tmp[256];
    __shared__ float s_qm[128];
    __shared__ float s_ci[2][128];
    const int tid = threadIdx.x;
    const int bx  = blockIdx.x;

    if (bx >= 8) {
        // ---- rowdot: wave per row, two dots sharing the key loads
        const int lane = tid & 63, wave = tid >> 6;
        const int row  = (bx - 8) * 4 + wave;
        const f4* k4  = (const f4*)(key + (size_t)row * HDIM);
        const f4* g04 = (const f4*)g;
        const f4* g14 = (const f4*)(g + HDIM);
        float a0 = 0.f, a1 = 0.f;
        #pragma unroll
        for (int i = 0; i < 4; ++i) {
            const int idx = lane + 64 * i;
            f4 kv = k4[idx], v0 = g04[idx], v1 = g14[idx];
            a0 += kv.x * v0.x + kv.y * v0.y + kv.z * v0.z + kv.w * v0.w;
            a1 += kv.x * v1.x + kv.y * v1.y + kv.z * v1.z + kv.w * v1.w;
        }
        #pragma unroll
        for (int off = 32; off > 0; off >>= 1) {
            a0 += __shfl_down(a0, off);
            a1 += __shfl_down(a1, off);
        }
        if (lane == 0) { d0[row] = a0; d1[row] = a1; }
        return;
    }

    // ---- qmean for h in [bx*128, bx*128+128): split 256 part-rows over 2 halves
    const int h = tid & 127, half = tid >> 7;
    {
        float acc = 0.f;
        const int rbase = half * 128;
        #pragma unroll 8
        for (int r = 0; r < 128; ++r)
            acc += part[(size_t)(rbase + r) * HDIM + bx * 128 + h];
        s_tmp[tid] = acc;
        __syncthreads();
        if (tid < 128) s_qm[tid] = (s_tmp[tid] + s_tmp[tid + 128]) * (1.0f / (float)SEQ);
        __syncthreads();
    }
    // ---- cpart[bx][i] = sum_{h in range} qm[h] * Wa1[(128 + bx*128 + h)*128 + i]
    {
        const int i = tid & 127;
        const int hbase = half * 64;
        float acc = 0.f;
        #pragma unroll 8
        for (int hh = 0; hh < 64; ++hh)
            acc += s_qm[hbase + hh] * Wa1[(size_t)(FDIM + bx * 128 + hbase + hh) * FDIM + i];
        s_ci[half][i] = acc;
        __syncthreads();
        if (tid < 128) cpart[bx * 128 + tid] = s_ci[0][tid] + s_ci[1][tid];
    }
}

// ---------------------------------------------------------------------------
// K3: tiny head — reads only ~5 KB of precomputed partials.
//   a1[k][i] = tanh(ba1[i] + cmem[k][i] + sum_b cpart[b][i])
//   wc[k]    = 0.5 * sigmoid(ba2 + a1_k @ Wa2)
// ---------------------------------------------------------------------------
__global__ void __launch_bounds__(256)
k3_weight(const float* __restrict__ cmem, const float* __restrict__ cpart,
          const float* __restrict__ ba1, const float* __restrict__ Wa2,
          const float* __restrict__ ba2, float* __restrict__ wc) {
    __shared__ float s_a1[256];
    const int tid = threadIdx.x;
    const int i = tid & 127;
    float acc = ba1[i] + cmem[tid];
    #pragma unroll
    for (int b = 0; b < 8; ++b) acc += cpart[b * 128 + i];
    s_a1[tid] = tanhf(acc);
    __syncthreads();
    if (tid < 2) {
        float s = ba2[0];
        for (int j = 0; j < FDIM; ++j) s += s_a1[tid * FDIM + j] * Wa2[j];
        wc[tid] = 0.5f / (1.0f + expf(-s));
    }
}

// ---------------------------------------------------------------------------
// K4: out[r, c] = wc0*d0[c] + wc1*d1[c] — 268 MB broadcast write.
// Grid stride (4.19M float4) is a multiple of the row length (2048 float4),
// so each thread's combined float4 is invariant: compute once, store 4x (NT).
// ---------------------------------------------------------------------------
__global__ void __launch_bounds__(256)
k4_bcast(const float* __restrict__ d0, const float* __restrict__ d1,
         const float* __restrict__ wc, f4* __restrict__ out) {
    const size_t total  = (size_t)SEQ * SEQ / 4;              // 16,777,216 float4
    const size_t i0     = (size_t)blockIdx.x * blockDim.x + threadIdx.x;
    const size_t stride = (size_t)gridDim.x * blockDim.x;     // 4,194,304
    const float c0 = wc[0], c1 = wc[1];
    const int col = (int)(i0 & (SEQ / 4 - 1));
    f4 a = ((const f4*)d0)[col];
    f4 b = ((const f4*)d1)[col];
    f4 v = c0 * a + c1 * b;
    for (size_t i = i0; i < total; i += stride)
        __builtin_nontemporal_store(v, &out[i]);
}

extern "C" void kernel_launch(void* const* d_in, const int* in_sizes, int n_in,
                              void* d_out, int out_size, void* d_ws, size_t ws_size,
                              hipStream_t stream) {
    const float* query = (const float*)d_in[0];
    const float* key   = (const float*)d_in[1];
    const float* dg    = (const float*)d_in[2];
    const float* ts    = (const float*)d_in[3];
    const float* Wt1   = (const float*)d_in[4];
    const float* bt1   = (const float*)d_in[5];
    const float* Wt2   = (const float*)d_in[6];
    const float* bt2   = (const float*)d_in[7];
    const float* Wa1   = (const float*)d_in[8];
    const float* ba1   = (const float*)d_in[9];
    const float* Wa2   = (const float*)d_in[10];
    const float* ba2   = (const float*)d_in[11];
    const float* Wg    = (const float*)d_in[12];
    const float* bg    = (const float*)d_in[13];

    float* ws    = (float*)d_ws;
    float* part  = ws + WS_PART;
    float* g     = ws + WS_G;
    float* cmem  = ws + WS_CMEM;
    float* cpart = ws + WS_CPART;
    float* d0    = ws + WS_D0;
    float* d1    = ws + WS_D1;
    float* wc    = ws + WS_WC;

    k1_qsum_g<<<NPART + 5, 256, 0, stream>>>(query, ts, dg, Wt1, bt1, Wt2, bt2,
                                             Wg, bg, Wa1, part, g, cmem);
    k2_rowdot_qmean<<<SEQ / 4 + 8, 256, 0, stream>>>(key, part, Wa1, g, d0, d1, cpart);
    k3_weight<<<1, 256, 0, stream>>>(cmem, cpart, ba1, Wa2, ba2, wc);
    k4_bcast<<<16384, 256, 0, stream>>>(d0, d1, wc, (f4*)d_out);
}